// Round 10
// baseline (60.828 us; speedup 1.0000x reference)
//
#include <hip/hip_runtime.h>
#include <hip/hip_bf16.h>

// x[4096,2048] f32, w[2048,2048] f32, bias[2048] f32, indices = permutation of
// K axis applied to BOTH operands -> cancels out of the einsum; unused.
#define M_DIM 4096
#define N_DIM 2048
#define K_DIM 2048

// Barrier-free single-wave blocks (AITER K-loop pattern):
// block = 1 wave (64 thr), tile 128x64, BK=32, 64 K-tiles.
// Grid = 32x32 = 1024 blocks = 4 blocks/CU = 1 wave/SIMD on all 4 SIMDs.
// LDS: triple buffer x (A 8KB + B 4KB) = 36 KiB -> 4 blocks co-resident.
// NO s_barrier anywhere; ordering via counted vmcnt only (never 0 in loop).
#define BK 32
#define NT (K_DIM / BK)          // 64
#define BUF_EL 6144              // 12 KiB per buffer (A 4096 el + B 2048 el)

typedef __bf16 bf16x8 __attribute__((ext_vector_type(8)));
typedef float f32x4 __attribute__((ext_vector_type(4)));
typedef unsigned short u16x8 __attribute__((ext_vector_type(8)));

__device__ __forceinline__ unsigned short f32_to_bf16_rne(float f) {
  unsigned int u = __float_as_uint(f);
  u += 0x7fffu + ((u >> 16) & 1u);
  return (unsigned short)(u >> 16);
}

// ---- merged f32 -> bf16 conversion (row-major, verified) ----
__global__ __launch_bounds__(256) void cvt_both(
    const float* __restrict__ x, const float* __restrict__ w,
    unsigned short* __restrict__ out, int xn8, int totn8) {
  int i = blockIdx.x * 256 + threadIdx.x;
  if (i >= totn8) return;
  const float* src = (i < xn8) ? (x + (size_t)i * 8)
                               : (w + (size_t)(i - xn8) * 8);
  f32x4 a = reinterpret_cast<const f32x4*>(src)[0];
  f32x4 b = reinterpret_cast<const f32x4*>(src)[1];
  u16x8 o;
  o[0] = f32_to_bf16_rne(a[0]); o[1] = f32_to_bf16_rne(a[1]);
  o[2] = f32_to_bf16_rne(a[2]); o[3] = f32_to_bf16_rne(a[3]);
  o[4] = f32_to_bf16_rne(b[0]); o[5] = f32_to_bf16_rne(b[1]);
  o[6] = f32_to_bf16_rne(b[2]); o[7] = f32_to_bf16_rne(b[3]);
  reinterpret_cast<u16x8*>(out)[i] = o;
}

__device__ __forceinline__ void gload_lds16(const unsigned short* g, unsigned short* l) {
  __builtin_amdgcn_global_load_lds(
      (const __attribute__((address_space(1))) unsigned int*)g,
      (__attribute__((address_space(3))) unsigned int*)l, 16, 0, 0);
}

#define LD8(p) (*reinterpret_cast<const bf16x8*>(p))
#define VMWAIT_(n) asm volatile("s_waitcnt vmcnt(" #n ")" ::: "memory")
#define VMWAIT(n) VMWAIT_(n)

// LDS packed-line layout (per buffer): two BK=32 rows share one 128B line.
// Logical (row R, k-chunk qq): line L = R>>1, logical slot u = (R&1)*4 + qq,
// stored slot s = u ^ (L&7).  Read banks: per 16-lane quad, 2 lanes/slot ->
// conflict-free (m136: 2-way is free).  gload_lds dest is LINEAR (rule 21):
// lane l of issue j writes line j*8+(l>>3), slot l&7; global source is the
// inverse permutation: u = (l&7)^((l>>3)&7) -> row j*16 + 2*(l>>3) + (u>>2),
// k-chunk u&3.
__global__ __launch_bounds__(64, 1) void gemm_wave(
    const unsigned short* __restrict__ A,   // [M][K] bf16 bits
    const unsigned short* __restrict__ B,   // [N][K] bf16 bits
    const float* __restrict__ bias,         // [N]
    float* __restrict__ C) {                // [M][N] f32
  __shared__ unsigned short L[3 * BUF_EL];  // 36 KiB

  const int lane = threadIdx.x;             // 0..63 (1 wave)

  // 2D XCD swizzle: each XCD owns 8bm x 16bn (A 4MB + B 4MB chunk in L2).
  const int orig = blockIdx.x;              // 0..1023
  const int xcd  = orig & 7;
  const int idx  = orig >> 3;               // 0..127
  const int bm   = (xcd & 3) * 8 + (idx & 7);    // 0..31
  const int bn   = (xcd >> 2) * 16 + (idx >> 3); // 0..31

  // ---- staging source pointers (inverse-permuted global addresses) ----
  const int u    = (lane & 7) ^ ((lane >> 3) & 7);
  const int rloc = 2 * (lane >> 3) + (u >> 2);   // row within 16-row group
  const int kc   = (u & 3) * 8;                  // k element offset
  const unsigned short* Agp[8];
  const unsigned short* Bgp[4];
#pragma unroll
  for (int j = 0; j < 8; ++j)
    Agp[j] = A + (size_t)(bm * 128 + j * 16 + rloc) * K_DIM + kc;
#pragma unroll
  for (int j = 0; j < 4; ++j)
    Bgp[j] = B + (size_t)(bn * 64 + j * 16 + rloc) * K_DIM + kc;

  // 12 gloads per tile: A -> [buf][0..4096), B -> [buf][4096..6144).
#define STAGE(bufLit, kofs) do { \
    unsigned short* _d = &L[(bufLit) * BUF_EL + lane * 8]; \
    gload_lds16(Agp[0] + (kofs), _d); \
    gload_lds16(Agp[1] + (kofs), _d + 512); \
    gload_lds16(Agp[2] + (kofs), _d + 1024); \
    gload_lds16(Agp[3] + (kofs), _d + 1536); \
    gload_lds16(Agp[4] + (kofs), _d + 2048); \
    gload_lds16(Agp[5] + (kofs), _d + 2560); \
    gload_lds16(Agp[6] + (kofs), _d + 3072); \
    gload_lds16(Agp[7] + (kofs), _d + 3584); \
    unsigned short* _e = &L[(bufLit) * BUF_EL + 4096 + lane * 8]; \
    gload_lds16(Bgp[0] + (kofs), _e); \
    gload_lds16(Bgp[1] + (kofs), _e + 512); \
    gload_lds16(Bgp[2] + (kofs), _e + 1024); \
    gload_lds16(Bgp[3] + (kofs), _e + 1536); \
  } while (0)

  // ---- ds_read base (elements): fragment row R = f*16 + fr, k = qq*8.
  // addr = (f*8 + (fr>>1))*64 + (((fr&1)*4+qq) ^ ((fr>>1)&7))*8
  const int fr = lane & 15;
  const int qq = lane >> 4;
  const int rbase = (fr >> 1) * 64 + ((((fr & 1) * 4 + qq) ^ ((fr >> 1) & 7)) * 8);

  const f32x4 z = {0.f, 0.f, 0.f, 0.f};
  f32x4 acc[8][4];
#pragma unroll
  for (int i = 0; i < 8; ++i)
#pragma unroll
    for (int j = 0; j < 4; ++j) acc[i][j] = z;

  // double register sets (phase-ahead: reads for tile t+1 issued at tile t)
  bf16x8 Xa[8], Xb[4], Ya[8], Yb[4];

#define READ_SET(Sa, Sb, bufLit) do { \
    const unsigned short* _a = &L[(bufLit) * BUF_EL] + rbase; \
    const unsigned short* _b = &L[(bufLit) * BUF_EL + 4096] + rbase; \
    Sa[0] = LD8(_a);          Sa[1] = LD8(_a + 512); \
    Sa[2] = LD8(_a + 1024);   Sa[3] = LD8(_a + 1536); \
    Sa[4] = LD8(_a + 2048);   Sa[5] = LD8(_a + 2560); \
    Sa[6] = LD8(_a + 3072);   Sa[7] = LD8(_a + 3584); \
    Sb[0] = LD8(_b);          Sb[1] = LD8(_b + 512); \
    Sb[2] = LD8(_b + 1024);   Sb[3] = LD8(_b + 1536); \
  } while (0)

#define MFMA_SET(Sa, Sb) do { \
    __builtin_amdgcn_s_setprio(1); \
    _Pragma("unroll") \
    for (int mi = 0; mi < 8; ++mi) { \
      acc[mi][0] = __builtin_amdgcn_mfma_f32_16x16x32_bf16(Sa[mi], Sb[0], acc[mi][0], 0, 0, 0); \
      acc[mi][1] = __builtin_amdgcn_mfma_f32_16x16x32_bf16(Sa[mi], Sb[1], acc[mi][1], 0, 0, 0); \
      acc[mi][2] = __builtin_amdgcn_mfma_f32_16x16x32_bf16(Sa[mi], Sb[2], acc[mi][2], 0, 0, 0); \
      acc[mi][3] = __builtin_amdgcn_mfma_f32_16x16x32_bf16(Sa[mi], Sb[3], acc[mi][3], 0, 0, 0); \
    } \
    __builtin_amdgcn_s_setprio(0); \
  } while (0)

  // One tile step (no barriers): issue stage(t+2); vmcnt(12) => stage(t+1)
  // landed (12 newest = t+2's stay in flight); ds_read tile-(t+1) regs into
  // the other set; MFMA tile t.  Buffer safety: buf[(t+2)%3]'s last ds_reads
  // were issued at t-1 and retired before tile t's MFMA (in-order DS queue,
  // compiler-counted lgkmcnt) -- writes at t cannot overtake them.
#define TILE(stgB, rdB, Sra, Srb, Sma, Smb, kofs) do { \
    STAGE(stgB, kofs); \
    VMWAIT(12); \
    READ_SET(Sra, Srb, rdB); \
    MFMA_SET(Sma, Smb); \
  } while (0)

  // prologue: stage tiles 0,1; wait tile 0; read tile-0 regs into X.
  STAGE(0, 0);
  STAGE(1, BK);
  VMWAIT(12);
  READ_SET(Xa, Xb, 0);

  // main loop: tiles 0..59, 6-tile body (buffers %3 and sets X/Y literal).
  // Body entering tile T (T%6==0): pointers at kbase=T*BK; outstanding =
  // stage(T+1)'s 12 loads; X holds tile T.
#pragma unroll 1
  for (int s = 0; s < 10; ++s) {
    TILE(2, 1, Ya, Yb, Xa, Xb, 2 * BK);  // t=T+0: stage T+2, read T+1, mfma T
    TILE(0, 2, Xa, Xb, Ya, Yb, 3 * BK);  // t=T+1
    TILE(1, 0, Ya, Yb, Xa, Xb, 4 * BK);  // t=T+2
    TILE(2, 1, Xa, Xb, Ya, Yb, 5 * BK);  // t=T+3
    TILE(0, 2, Ya, Yb, Xa, Xb, 6 * BK);  // t=T+4
    TILE(1, 0, Xa, Xb, Ya, Yb, 7 * BK);  // t=T+5
#pragma unroll
    for (int j = 0; j < 8; ++j) Agp[j] += 6 * BK;
#pragma unroll
    for (int j = 0; j < 4; ++j) Bgp[j] += 6 * BK;
  }

  // tail: tiles 60..63 (kbase = 60*BK, pointers already advanced).
  TILE(2, 1, Ya, Yb, Xa, Xb, 2 * BK);    // t=60: stage 62, read 61, mfma 60
  TILE(0, 2, Xa, Xb, Ya, Yb, 3 * BK);    // t=61: stage 63, read 62, mfma 61
  VMWAIT(0);                              // t=62: tile 63 landed
  READ_SET(Ya, Yb, 0);                    //       read tile-63 regs (buf 63%3=0)
  MFMA_SET(Xa, Xb);                       //       mfma 62
  MFMA_SET(Ya, Yb);                       // t=63

  // ---- epilogue: C/D layout col = lane&15, row = (lane>>4)*4 + r ----
  const int orow0 = bm * 128 + qq * 4;
  const int ocol0 = bn * 64 + fr;
#pragma unroll
  for (int ni = 0; ni < 4; ++ni) {
    const int col = ocol0 + ni * 16;
    const float bvv = bias[col];
#pragma unroll
    for (int mi = 0; mi < 8; ++mi) {
      const int row = orow0 + mi * 16;
#pragma unroll
      for (int r = 0; r < 4; ++r)
        C[(size_t)(row + r) * N_DIM + col] = acc[mi][ni][r] + bvv;
    }
  }
#undef TILE
#undef MFMA_SET
#undef READ_SET
#undef STAGE
}

// ---- safety fallback ----
__global__ __launch_bounds__(256) void gemm_f32_naive(
    const float* __restrict__ X, const float* __restrict__ W,
    const float* __restrict__ bias, float* __restrict__ C) {
  int o = blockIdx.x * 256 + threadIdx.x;
  if (o >= M_DIM * N_DIM) return;
  int m = o / N_DIM, n = o % N_DIM;
  const float* xr = X + (size_t)m * K_DIM;
  const float* wr = W + (size_t)n * K_DIM;
  float s = 0.f;
  for (int k = 0; k < K_DIM; ++k) s += xr[k] * wr[k];
  C[o] = s + bias[n];
}

extern "C" void kernel_launch(void* const* d_in, const int* in_sizes, int n_in,
                              void* d_out, int out_size, void* d_ws, size_t ws_size,
                              hipStream_t stream) {
  const float* x    = (const float*)d_in[0];
  const float* w    = (const float*)d_in[1];
  const float* bias = (const float*)d_in[2];
  float* out = (float*)d_out;

  const size_t x_elems = (size_t)M_DIM * K_DIM;
  const size_t w_elems = (size_t)N_DIM * K_DIM;
  const size_t need = (x_elems + w_elems) * sizeof(unsigned short);

  if (ws_size < need) {
    gemm_f32_naive<<<(M_DIM * N_DIM + 255) / 256, 256, 0, stream>>>(x, w, bias, out);
    return;
  }

  unsigned short* xb = (unsigned short*)d_ws;
  unsigned short* wb = xb + x_elems;

  const int xn8 = (int)(x_elems / 8);
  const int totn8 = (int)((x_elems + w_elems) / 8);
  cvt_both<<<(totn8 + 255) / 256, 256, 0, stream>>>(x, w, xb, xn8, totn8);

  // (4096/128) x (2048/64) = 32 x 32 = 1024 single-wave blocks = 4/CU.
  gemm_wave<<<1024, 64, 0, stream>>>(xb, wb, bias, out);
}

// Round 11
// 55.714 us; speedup vs baseline: 1.0918x; 1.0918x over previous
//
#include <hip/hip_runtime.h>
#include <hip/hip_bf16.h>

// x[4096,2048] f32, w[2048,2048] f32, bias[2048] f32, indices = permutation of
// K axis applied to BOTH operands -> cancels out of the einsum; unused.
#define M_DIM 4096
#define N_DIM 2048
#define K_DIM 2048

// R6 skeleton (2 blocks/CU, 4 waves, 128x128) + BK=32 triple-buffer with
// counted vmcnt(4) (no per-tile drain) + R10's packed-line LDS layout
// (0 conflicts at BK=32) + R9's 2D XCD swizzle (FETCH halved).
#define BM 128
#define BN 128
#define BK 32
#define NT (K_DIM / BK)      // 64 K-tiles
#define A_TILE (BM * BK)     // 4096 elems = 8 KiB
#define B_TILE (BN * BK)     // 4096 elems = 8 KiB

typedef __bf16 bf16x8 __attribute__((ext_vector_type(8)));
typedef float f32x4 __attribute__((ext_vector_type(4)));
typedef unsigned short u16x8 __attribute__((ext_vector_type(8)));

__device__ __forceinline__ unsigned short f32_to_bf16_rne(float f) {
  unsigned int u = __float_as_uint(f);
  u += 0x7fffu + ((u >> 16) & 1u);
  return (unsigned short)(u >> 16);
}

// ---- merged f32 -> bf16 conversion (row-major, verified) ----
__global__ __launch_bounds__(256) void cvt_both(
    const float* __restrict__ x, const float* __restrict__ w,
    unsigned short* __restrict__ out, int xn8, int totn8) {
  int i = blockIdx.x * 256 + threadIdx.x;
  if (i >= totn8) return;
  const float* src = (i < xn8) ? (x + (size_t)i * 8)
                               : (w + (size_t)(i - xn8) * 8);
  f32x4 a = reinterpret_cast<const f32x4*>(src)[0];
  f32x4 b = reinterpret_cast<const f32x4*>(src)[1];
  u16x8 o;
  o[0] = f32_to_bf16_rne(a[0]); o[1] = f32_to_bf16_rne(a[1]);
  o[2] = f32_to_bf16_rne(a[2]); o[3] = f32_to_bf16_rne(a[3]);
  o[4] = f32_to_bf16_rne(b[0]); o[5] = f32_to_bf16_rne(b[1]);
  o[6] = f32_to_bf16_rne(b[2]); o[7] = f32_to_bf16_rne(b[3]);
  reinterpret_cast<u16x8*>(out)[i] = o;
}

__device__ __forceinline__ void gload_lds16(const unsigned short* g, unsigned short* l) {
  __builtin_amdgcn_global_load_lds(
      (const __attribute__((address_space(1))) unsigned int*)g,
      (__attribute__((address_space(3))) unsigned int*)l, 16, 0, 0);
}

#define LD8(p) (*reinterpret_cast<const bf16x8*>(p))
#define VMWAIT_(n) asm volatile("s_waitcnt vmcnt(" #n ")" ::: "memory")
#define VMWAIT(n) VMWAIT_(n)
#define SBAR() __builtin_amdgcn_s_barrier()
#define SCHED() __builtin_amdgcn_sched_barrier(0)

// Packed-line LDS layout (R10-verified, 0 conflicts): two BK=32 rows per
// 128B line. (row R, k-chunk q): line = R>>1, logical slot u = (R&1)*4+q,
// stored slot = u ^ (line&7).  gload_lds dest LINEAR; global source is the
// inverse permutation (rule 21).
__global__ __launch_bounds__(256, 2) void gemm_tb(
    const unsigned short* __restrict__ A,   // [M][K] bf16 bits
    const unsigned short* __restrict__ B,   // [N][K] bf16 bits
    const float* __restrict__ bias,         // [N]
    float* __restrict__ C) {                // [M][N] f32
  __shared__ unsigned short As[3 * A_TILE]; // 24 KiB
  __shared__ unsigned short Bs[3 * B_TILE]; // 24 KiB

  const int tid  = threadIdx.x;   // 0..255
  const int lane = tid & 63;
  const int wave = tid >> 6;      // 0..3
  const int wr   = wave >> 1;     // 0..1 (M)
  const int wc   = wave & 1;      // 0..1 (N)

  // 2D XCD swizzle (R9-verified): each XCD owns an 8bm x 8bn chunk.
  const int orig = blockIdx.x;    // 0..511
  const int xcd  = orig & 7;
  const int idx  = orig >> 3;     // 0..63
  const int bm   = (xcd & 3) * 8 + (idx & 7);   // 0..31
  const int bn   = (xcd >> 2) * 8 + (idx >> 3); // 0..15

  // ---- staging source (inverse-permuted global addresses) ----
  // dest: tid -> line tid>>3, slot tid&7 (linear). One issue = 32 lines
  // = 64 rows.  u = slot ^ (line&7); row-in-64 = 2*line + (u>>2) (line%32),
  // k-chunk = u&3.
  const int lid  = tid >> 3;                    // 0..31 (line within issue)
  const int uu   = (tid & 7) ^ (lid & 7);
  const int grow = 2 * lid + (uu >> 2);         // 0..63
  const int kc   = (uu & 3) * 8;                // k element offset
  const unsigned short* Ag[2];
  const unsigned short* Bg[2];
#pragma unroll
  for (int j = 0; j < 2; ++j) {
    Ag[j] = A + (size_t)(bm * BM + j * 64 + grow) * K_DIM + kc;
    Bg[j] = B + (size_t)(bn * BN + j * 64 + grow) * K_DIM + kc;
  }

  // 4 gloads per tile (A 2 + B 2).
#define STAGE(bufLit, k0) do { \
    unsigned short* _da = &As[(bufLit) * A_TILE + tid * 8]; \
    unsigned short* _db = &Bs[(bufLit) * B_TILE + tid * 8]; \
    gload_lds16(Ag[0] + (k0), _da); \
    gload_lds16(Ag[1] + (k0), _da + 2048); \
    gload_lds16(Bg[0] + (k0), _db); \
    gload_lds16(Bg[1] + (k0), _db + 2048); \
  } while (0)

  // ---- ds_read offsets (elements): row R, k-chunk qq:
  // addr = (R>>1)*64 + (((R&1)*4+qq) ^ ((R>>1)&7))*8
  const int fr = lane & 15;
  const int qq = lane >> 4;
  int aoff[4], boff[4];
#pragma unroll
  for (int mi = 0; mi < 4; ++mi) {
    const int R = wr * 64 + mi * 16 + fr;
    aoff[mi] = (R >> 1) * 64 + ((((R & 1) * 4 + qq) ^ ((R >> 1) & 7)) * 8);
  }
#pragma unroll
  for (int ni = 0; ni < 4; ++ni) {
    const int R = wc * 64 + ni * 16 + fr;
    boff[ni] = (R >> 1) * 64 + ((((R & 1) * 4 + qq) ^ ((R >> 1) & 7)) * 8);
  }

  const f32x4 z = {0.f, 0.f, 0.f, 0.f};
  f32x4 acc[4][4];
#pragma unroll
  for (int i = 0; i < 4; ++i)
#pragma unroll
    for (int j = 0; j < 4; ++j) acc[i][j] = z;

  // double register sets (phase-ahead across the barrier, R6-verified)
  bf16x8 Xa[4], Xb[4], Ya[4], Yb[4];

#define READ_SET(Sa, Sb, bufLit) do { \
    const unsigned short* _a = &As[(bufLit) * A_TILE]; \
    const unsigned short* _b = &Bs[(bufLit) * B_TILE]; \
    Sb[0] = LD8(_b + boff[0]); Sb[1] = LD8(_b + boff[1]); \
    Sb[2] = LD8(_b + boff[2]); Sb[3] = LD8(_b + boff[3]); \
    Sa[0] = LD8(_a + aoff[0]); Sa[1] = LD8(_a + aoff[1]); \
    Sa[2] = LD8(_a + aoff[2]); Sa[3] = LD8(_a + aoff[3]); \
  } while (0)

#define MFMA_SET(Sa, Sb) do { \
    __builtin_amdgcn_s_setprio(1); \
    _Pragma("unroll") \
    for (int mi = 0; mi < 4; ++mi) { \
      acc[mi][0] = __builtin_amdgcn_mfma_f32_16x16x32_bf16(Sa[mi], Sb[0], acc[mi][0], 0, 0, 0); \
      acc[mi][1] = __builtin_amdgcn_mfma_f32_16x16x32_bf16(Sa[mi], Sb[1], acc[mi][1], 0, 0, 0); \
      acc[mi][2] = __builtin_amdgcn_mfma_f32_16x16x32_bf16(Sa[mi], Sb[2], acc[mi][2], 0, 0, 0); \
      acc[mi][3] = __builtin_amdgcn_mfma_f32_16x16x32_bf16(Sa[mi], Sb[3], acc[mi][3], 0, 0, 0); \
    } \
    __builtin_amdgcn_s_setprio(0); \
  } while (0)

  // Tile t: cur set holds tile t (read last tile). Stage t+2 (distance 2,
  // buffer freed before SBAR(t-1)); MFMA t; vmcnt(4) => stage(t+1) landed
  // (t+2's 4 loads stay in flight -- never drain); barrier; read t+1 regs.
#define TILE(stgB, rdB, Scur_a, Scur_b, Snxt_a, Snxt_b, k0) do { \
    STAGE(stgB, k0); \
    MFMA_SET(Scur_a, Scur_b); \
    VMWAIT(4); \
    SBAR(); \
    SCHED(); \
    READ_SET(Snxt_a, Snxt_b, rdB); \
  } while (0)

  // prologue: stage tiles 0,1; wait tile 0 (leave tile 1's 4 in flight).
  STAGE(0, 0);
  STAGE(1, BK);
  VMWAIT(4);
  SBAR();
  SCHED();
  READ_SET(Xa, Xb, 0);

  // main loop: tiles 0..59 (staging 2..61), 6-tile body for literal bufs.
#pragma unroll 1
  for (int s = 0; s < 10; ++s) {
    const int kb = (6 * s + 2) * BK;
    TILE(2, 1, Xa, Xb, Ya, Yb, kb);            // t=6s+0
    TILE(0, 2, Ya, Yb, Xa, Xb, kb + BK);       // t=6s+1
    TILE(1, 0, Xa, Xb, Ya, Yb, kb + 2 * BK);   // t=6s+2
    TILE(2, 1, Ya, Yb, Xa, Xb, kb + 3 * BK);   // t=6s+3
    TILE(0, 2, Xa, Xb, Ya, Yb, kb + 4 * BK);   // t=6s+4
    TILE(1, 0, Ya, Yb, Xa, Xb, kb + 5 * BK);   // t=6s+5
  }

  // tail: tiles 60..63 (stage 62, 63; then drain once).
  TILE(2, 1, Xa, Xb, Ya, Yb, 62 * BK);         // t=60: stage 62 -> buf2
  TILE(0, 2, Ya, Yb, Xa, Xb, 63 * BK);         // t=61: stage 63 -> buf0
  // t=62: no staging; drain stage(63); read tile-63 regs from buf0.
  MFMA_SET(Xa, Xb);
  VMWAIT(0);
  SBAR();
  SCHED();
  READ_SET(Ya, Yb, 0);
  MFMA_SET(Ya, Yb);                            // t=63

  // ---- epilogue: C/D layout col = lane&15, row = (lane>>4)*4 + r ----
  const int orow0 = bm * BM + wr * 64 + qq * 4;
  const int ocol0 = bn * BN + wc * 64 + fr;
#pragma unroll
  for (int ni = 0; ni < 4; ++ni) {
    const int col = ocol0 + ni * 16;
    const float bvv = bias[col];
#pragma unroll
    for (int mi = 0; mi < 4; ++mi) {
      const int row = orow0 + mi * 16;
#pragma unroll
      for (int r = 0; r < 4; ++r)
        C[(size_t)(row + r) * N_DIM + col] = acc[mi][ni][r] + bvv;
    }
  }
#undef TILE
#undef MFMA_SET
#undef READ_SET
#undef STAGE
}

// ---- safety fallback ----
__global__ __launch_bounds__(256) void gemm_f32_naive(
    const float* __restrict__ X, const float* __restrict__ W,
    const float* __restrict__ bias, float* __restrict__ C) {
  int o = blockIdx.x * 256 + threadIdx.x;
  if (o >= M_DIM * N_DIM) return;
  int m = o / N_DIM, n = o % N_DIM;
  const float* xr = X + (size_t)m * K_DIM;
  const float* wr = W + (size_t)n * K_DIM;
  float s = 0.f;
  for (int k = 0; k < K_DIM; ++k) s += xr[k] * wr[k];
  C[o] = s + bias[n];
}

extern "C" void kernel_launch(void* const* d_in, const int* in_sizes, int n_in,
                              void* d_out, int out_size, void* d_ws, size_t ws_size,
                              hipStream_t stream) {
  const float* x    = (const float*)d_in[0];
  const float* w    = (const float*)d_in[1];
  const float* bias = (const float*)d_in[2];
  float* out = (float*)d_out;

  const size_t x_elems = (size_t)M_DIM * K_DIM;
  const size_t w_elems = (size_t)N_DIM * K_DIM;
  const size_t need = (x_elems + w_elems) * sizeof(unsigned short);

  if (ws_size < need) {
    gemm_f32_naive<<<(M_DIM * N_DIM + 255) / 256, 256, 0, stream>>>(x, w, bias, out);
    return;
  }

  unsigned short* xb = (unsigned short*)d_ws;
  unsigned short* wb = xb + x_elems;

  const int xn8 = (int)(x_elems / 8);
  const int totn8 = (int)((x_elems + w_elems) / 8);
  cvt_both<<<(totn8 + 255) / 256, 256, 0, stream>>>(x, w, xb, xn8, totn8);

  // (2048/128) x (4096/128) = 16 x 32 = 512 blocks = 2/CU.
  gemm_tb<<<512, 256, 0, stream>>>(xb, wb, bias, out);
}